// Round 10
// baseline (322.349 us; speedup 1.0000x reference)
//
#include <hip/hip_runtime.h>
#include <math.h>

#define BB 4
#define NN1 4096
#define NN2 1024
#define DS 128
#define DD 64
#define DOUT 256
#define M1 16384        // BB*NN1
#define MH 262144       // M1*16
#define KCAT 192        // DS+DD
#define KI 8            // interp k
#define KN 16           // neighbor k
#define POOLCAP 512     // in-cap candidate pool per query (R23)

#define OUT_P1 49152
#define OUT_X  49152
#define OUT_O1 4243456

// coordinates pre-scaled by 2^14 in prolog -> d^2 is directly the 2^28 fixed-point key
// pair-SoA additionally stores 2*x,2*y,2*z so d^2 = (qn+cn) - x2*qx - y2*qy - z2*qz

// ---- workspace layout (float offsets) ----
static const size_t OFF_WTS  = 16777216;               // swizzled weights (hi/lo)
static const size_t OFF_TMP  = 33554432;
static const size_t OFF_XD   = OFF_TMP  + 2097152;     // bf16 qw (M1*128)
static const size_t OFF_XI   = OFF_XD   + 2097152;
static const size_t OFF_Q    = OFF_XI   + 2097152;     // bf16 q
static const size_t OFF_K    = OFF_Q    + 2097152;     // bf16 e = xd - k
static const size_t OFF_V    = OFF_K    + 2097152;     // bf16 v2 = v + xd
static const size_t OFF_OUTP = OFF_V    + 2097152;     // bf16 ew (then out-mlp C f32)
static const size_t OFF_NIDX = OFF_OUTP + 4194304;
static const size_t OFF_STAT = OFF_NIDX + 262144;      // 3072 floats
static const size_t OFF_P1Q  = OFF_STAT + 4096;        // 16384 float4 (AoS, scaled)
static const size_t OFF_P2Q  = OFF_P1Q  + 65536;       // 4096 float4 (AoS, scaled)
static const size_t OFF_P1S  = OFF_P2Q  + 16384;       // pair-SoA p1 (65536 floats)
static const size_t OFF_P2S  = OFF_P1S  + 65536;       // pair-SoA p2 (16384 floats)

// ushort offsets inside the weights region
#define WDH 0
#define WDL 8192
#define WQH 16384
#define WQL 32768
#define WKH 49152
#define WKL 65536
#define WVH 81920
#define WVL 98304
#define W1H 114688
#define W1L 131072
#define W2H 147456
#define W2L 163840
#define WOH 180224
#define WOL 229376

typedef __attribute__((ext_vector_type(8))) short short8;
typedef __attribute__((ext_vector_type(4))) float floatx4;
typedef __attribute__((ext_vector_type(2))) float float2v;

__device__ inline unsigned short f2bf(float f) {
    union { float f; unsigned int u; } x; x.f = f;
    unsigned int r = x.u + 0x7fffu + ((x.u >> 16) & 1u);
    return (unsigned short)(r >> 16);
}
__device__ inline float bf2f(unsigned short h) {
    union { unsigned int u; float f; } x; x.u = ((unsigned int)h) << 16;
    return x.f;
}
__device__ inline unsigned long long shfl_xor_u64(unsigned long long v, int m) {
    unsigned lo = (unsigned)v, hi = (unsigned)(v >> 32);
    lo = (unsigned)__shfl_xor((int)lo, m);
    hi = (unsigned)__shfl_xor((int)hi, m);
    return ((unsigned long long)hi << 32) | lo;
}
// 2×f32 -> packed 2×bf16 (RNE; matches f2bf)
__device__ inline unsigned cvt_pk_bf16(float lo, float hi) {
    unsigned r;
    asm volatile("v_cvt_pk_bf16_f32 %0, %1, %2" : "=v"(r) : "v"(lo), "v"(hi));
    return r;
}

// --------- prolog + swizzle merged: copyout, stat zero, point pack, W swizzle
#define PRO_STAT  (OUT_P1 + BB)          // 49156
#define PRO_PACK  (PRO_STAT + 3072)      // 52228
#define PRO_TOTAL (PRO_PACK + M1 + BB*NN2)   // 72708
#define NPRO 285
struct SwzParams {
    const float* W[7];
    unsigned short* hi[7];
    unsigned short* lo[7];
    int N[7];
    int fid0[8];
};
__global__ __launch_bounds__(256) void k_prolog(
    const float* __restrict__ p1, const int* __restrict__ o1,
    const float* __restrict__ p2, float* __restrict__ out,
    float* __restrict__ stat, float4* __restrict__ p1q,
    float4* __restrict__ p2q, float* __restrict__ p1s,
    float* __restrict__ p2s, SwzParams p)
{
    if (blockIdx.x < NPRO) {
        int i = blockIdx.x * 256 + threadIdx.x;
        if (i < OUT_P1) out[i] = p1[i];
        else if (i < PRO_STAT) out[OUT_O1 + (i - OUT_P1)] = (float)o1[i - OUT_P1];
        else if (i < PRO_PACK) stat[i - PRO_STAT] = 0.f;
        else if (i < PRO_TOTAL) {
            int j = i - PRO_PACK;
            const float* src; float4* dst; float* ps; int jj;
            if (j < M1) { src = p1; dst = p1q; ps = p1s; jj = j; }
            else        { src = p2; dst = p2q; ps = p2s; jj = j - M1; }
            // scale by 2^14 (exact): d^2 in scaled space == 2^28 fixed-point key
            float x = src[jj*3+0] * 16384.f;
            float y = src[jj*3+1] * 16384.f;
            float z = src[jj*3+2] * 16384.f;
            float n = fmaf(z, z, fmaf(y, y, x*x));
            dst[jj] = make_float4(x, y, z, n);
            int pb8 = (jj >> 1)*8 + (jj & 1);   // pair-SoA: 2x0 2x1 2y0 2y1 2z0 2z1 w0 w1
            ps[pb8]   = x + x; ps[pb8+2] = y + y;
            ps[pb8+4] = z + z; ps[pb8+6] = n;
        }
        return;
    }
    int fid = (blockIdx.x - NPRO)*4 + (threadIdx.x >> 6);
    int lane = threadIdx.x & 63;
    if (fid >= 272) return;
    int seg = 0;
    #pragma unroll
    for (int i = 1; i < 7; i++) if (fid >= p.fid0[i]) seg = i;
    int f = fid - p.fid0[seg];
    const float* W = p.W[seg];
    int N = p.N[seg];
    int ncj = N >> 4;
    int slab = f / ncj, cj = f - slab*ncj;
    int n  = cj*16 + (lane & 15);
    int k0 = slab*32 + (lane >> 4)*8;
    unsigned int oh[8], ol[8];
    #pragma unroll
    for (int j = 0; j < 8; j++) {
        float v = W[(size_t)(k0 + j) * N + n];
        unsigned short h = f2bf(v);
        oh[j] = h;
        ol[j] = f2bf(v - bf2f(h));
    }
    uint4 ph, pl;
    ph.x = oh[0] | (oh[1] << 16); ph.y = oh[2] | (oh[3] << 16);
    ph.z = oh[4] | (oh[5] << 16); ph.w = oh[6] | (oh[7] << 16);
    pl.x = ol[0] | (ol[1] << 16); pl.y = ol[2] | (ol[3] << 16);
    pl.z = ol[4] | (ol[5] << 16); pl.w = ol[6] | (ol[7] << 16);
    ((uint4*)p.hi[seg])[f*64 + lane] = ph;
    ((uint4*)p.lo[seg])[f*64 + lane] = pl;
}

// ----------------------------- split-bf16 MFMA GEMM (near-fp32 via hi/lo x 3)
// MODE 0: A plain. MODE 2: A = concat(Amat, aux). MODE 3: qkv, bf16 out —
//   seg0: q = bn(tmp)@Wq ; seg1: e = bn(tmp) - xi@Wk ; seg2: v2 = xi@Wv + bn(tmp).
// NSPL: N-dimension split — each block computes ncj/NSPL col-groups.
template<int N, int K, int MODE, int STATS, int BNA, int NSPL>
__global__ __launch_bounds__(256) void k_gemm_mf(
    const float* __restrict__ Amat, const unsigned short* __restrict__ Whi,
    const unsigned short* __restrict__ Wlo, const float* __restrict__ bias,
    float* __restrict__ C, const float* __restrict__ aux,
    float* __restrict__ sums, float* __restrict__ sumsq,
    const float* __restrict__ bsums, const float* __restrict__ bsumsq,
    const float* __restrict__ bg, const float* __restrict__ bbt)
{
    constexpr int ncj  = N >> 4;
    constexpr int ncjL = ncj / NSPL;     // col-groups per block
    constexpr int NL   = ncjL * 16;      // cols per block
    __shared__ float sstat[STATS ? 2*NL : 1];
    __shared__ float sbn[BNA ? 2*DS : 1];
    const int t = threadIdx.x, w = t >> 6, lane = t & 63;
    const int quad = lane >> 4, c = lane & 15;
    const int row = blockIdx.x*64 + w*16 + c;
    const int sA = (MODE == 2) ? DS : K;
    constexpr int nslab = K >> 5;
    const int seg = (MODE == 3) ? blockIdx.y : 0;
    const int yn  = (MODE == 3) ? blockIdx.z : blockIdx.y;
    const int cj0 = yn * ncjL;
    const float* Abase = (MODE == 3 && seg > 0) ? aux : Amat;
    const unsigned short* WhiS = Whi + (size_t)seg*32768;
    const unsigned short* WloS = Wlo + (size_t)seg*32768;
    float* CS = C + (size_t)seg*2097152;
    unsigned short* CS16 = (unsigned short*)C + (size_t)seg*4194304;
    if (STATS) {
        for (int i = t; i < 2*NL; i += 256) sstat[i] = 0.f;
    }
    if (BNA) {
        if (t < DS) {
            const float invM = 1.f / (float)M1;
            float m   = bsums[t] * invM;
            float var = bsumsq[t] * invM - m*m;
            float sc  = bg[t] * rsqrtf(var + 1e-5f);
            sbn[t] = sc;
            sbn[DS + t] = bbt[t] - m * sc;
        }
    }
    if (STATS || BNA) __syncthreads();

    floatx4 acc[ncjL];
    #pragma unroll
    for (int cj = 0; cj < ncjL; cj++) acc[cj] = (floatx4){0.f,0.f,0.f,0.f};

    #pragma unroll
    for (int slab = 0; slab < nslab; slab++) {
        const int kk = slab*32 + quad*8;
        const float* src;
        if (MODE == 2 && kk >= DS) src = aux + (size_t)row*DD + (kk - DS);
        else                       src = Abase + (size_t)row*sA + kk;
        floatx4 va = *(const floatx4*)src;
        floatx4 vb = *(const floatx4*)(src + 4);
        if (BNA && MODE == 3 && seg == 0) {
            #pragma unroll
            for (int j = 0; j < 4; j++) {
                va[j] = fmaxf(fmaf(va[j], sbn[kk+j],   sbn[DS+kk+j]),   0.f);
                vb[j] = fmaxf(fmaf(vb[j], sbn[kk+4+j], sbn[DS+kk+4+j]), 0.f);
            }
        }
        short8 ahi, alo;
        #pragma unroll
        for (int j = 0; j < 4; j++) {
            unsigned short h = f2bf(va[j]);
            ahi[j] = (short)h; alo[j] = (short)f2bf(va[j] - bf2f(h));
        }
        #pragma unroll
        for (int j = 0; j < 4; j++) {
            unsigned short h = f2bf(vb[j]);
            ahi[4+j] = (short)h; alo[4+j] = (short)f2bf(vb[j] - bf2f(h));
        }
        const short8* bh = (const short8*)WhiS + (size_t)slab*ncj*64;
        const short8* bl = (const short8*)WloS + (size_t)slab*ncj*64;
        #pragma unroll
        for (int cj = 0; cj < ncjL; cj++) {
            short8 bhv = bh[(cj0 + cj)*64 + lane];
            short8 blv = bl[(cj0 + cj)*64 + lane];
            acc[cj] = __builtin_amdgcn_mfma_f32_16x16x32_bf16(alo, bhv, acc[cj], 0, 0, 0);
            acc[cj] = __builtin_amdgcn_mfma_f32_16x16x32_bf16(ahi, blv, acc[cj], 0, 0, 0);
            acc[cj] = __builtin_amdgcn_mfma_f32_16x16x32_bf16(ahi, bhv, acc[cj], 0, 0, 0);
        }
    }
    const int rbase = blockIdx.x*64 + w*16 + quad*4;
    #pragma unroll
    for (int cj = 0; cj < ncjL; cj++) {
        const int colG = (cj0 + cj)*16 + c;
        const float bb = bias ? bias[colG] : 0.f;
        float s = 0.f, ss = 0.f;
        #pragma unroll
        for (int p = 0; p < 4; p++) {
            float v = acc[cj][p] + bb;
            if (MODE == 3) {
                if (seg > 0) {
                    float xv = Amat[(size_t)(rbase + p)*DS + colG];
                    if (BNA) xv = fmaxf(fmaf(xv, sbn[colG], sbn[DS+colG]), 0.f);
                    if (seg == 1) v = xv - v;     // e = xd - k
                    else          v += xv;        // v2 = v + xd
                }
                CS16[(size_t)(rbase + p)*N + colG] = f2bf(v);
            } else {
                CS[(size_t)(rbase + p)*N + colG] = v;
            }
            if (STATS) { s += v; ss += v*v; }
        }
        if (STATS) {
            s  += __shfl_xor(s, 16);  s  += __shfl_xor(s, 32);
            ss += __shfl_xor(ss, 16); ss += __shfl_xor(ss, 32);
            if (quad == 0) {
                atomicAdd(&sstat[cj*16 + c], s);
                atomicAdd(&sstat[NL + cj*16 + c], ss);
            }
        }
    }
    if (STATS) {
        __syncthreads();
        for (int i = t; i < NL; i += 256) {
            atomicAdd(&sums[cj0*16 + i],  sstat[i]);
            atomicAdd(&sumsq[cj0*16 + i], sstat[NL + i]);
        }
    }
}

// -------------------- qW1 / eW1 dense bf16 GEMMs (h = q+e linearity), bf16 out
// y==0: qw = q16 @ W1hi ; y==1: ew = e16 @ W1hi + b1.  z: N-split x4 (R23).
__global__ __launch_bounds__(256) void k_gemm_qe(
    const unsigned short* __restrict__ q16, const unsigned short* __restrict__ e16,
    const unsigned short* __restrict__ W1hi, const float* __restrict__ b1,
    unsigned short* __restrict__ qw, unsigned short* __restrict__ ew)
{
    const int t = threadIdx.x, w = t >> 6, lane = t & 63;
    const int quad = lane >> 4, c = lane & 15;
    const int y = blockIdx.y;
    const int cj0 = blockIdx.z * 2;
    const unsigned short* A = y ? e16 : q16;
    unsigned short* C16 = y ? ew : qw;
    const int row = blockIdx.x*64 + w*16 + c;

    floatx4 acc[2];
    #pragma unroll
    for (int cj = 0; cj < 2; cj++) acc[cj] = (floatx4){0.f,0.f,0.f,0.f};

    #pragma unroll
    for (int slab = 0; slab < 4; slab++) {
        uint4 av = *(const uint4*)(A + (size_t)row*DS + slab*32 + quad*8);
        short8 af;
        ((uint4*)&af)[0] = av;
        const short8* bh = (const short8*)W1hi + (size_t)slab*8*64;
        #pragma unroll
        for (int cj = 0; cj < 2; cj++) {
            short8 bhv = bh[(cj0 + cj)*64 + lane];
            acc[cj] = __builtin_amdgcn_mfma_f32_16x16x32_bf16(af, bhv, acc[cj], 0, 0, 0);
        }
    }
    const int rbase = blockIdx.x*64 + w*16 + quad*4;
    #pragma unroll
    for (int cj = 0; cj < 2; cj++) {
        const int colG = (cj0 + cj)*16 + c;
        const float bb = y ? b1[colG] : 0.f;
        #pragma unroll
        for (int p = 0; p < 4; p++)
            C16[(size_t)(rbase + p)*DS + colG] = f2bf(acc[cj][p] + bb);
    }
}

// -------------------- BN stats over h WITHOUT materializing h (bf16 streams)
// per gp (query): sum_c (a+b_c) = 16a + B1 ; sum_c (a+b_c)^2 = 16a^2 + 2a*B1 + B2
__global__ __launch_bounds__(256) void k_hstat(
    const unsigned short* __restrict__ qw, const unsigned short* __restrict__ ew,
    const int* __restrict__ nidx,
    float* __restrict__ sums, float* __restrict__ sumsq)
{
    __shared__ float sstat[256];
    const int t = threadIdx.x, w = t >> 6, lane = t & 63;
    sstat[t] = 0.f;
    __syncthreads();
    const int col = lane*2;
    float Sx = 0.f, Sy = 0.f, SSx = 0.f, SSy = 0.f;
    #pragma unroll
    for (int g2 = 0; g2 < 4; g2++) {
        const int gp = blockIdx.x*16 + w*4 + g2;
        unsigned av = *(const unsigned*)(qw + (size_t)gp*DS + col);
        float ax = bf2f((unsigned short)(av & 0xffffu));
        float ay = bf2f((unsigned short)(av >> 16));
        float B1x = 0.f, B1y = 0.f, B2x = 0.f, B2y = 0.f;
        const int* np = nidx + gp*16;
        #pragma unroll
        for (int cc = 0; cc < 16; cc++) {
            int m = np[cc];
            unsigned bv = *(const unsigned*)(ew + (size_t)m*DS + col);
            float bx = bf2f((unsigned short)(bv & 0xffffu));
            float by = bf2f((unsigned short)(bv >> 16));
            B1x += bx; B1y += by;
            B2x = fmaf(bx, bx, B2x); B2y = fmaf(by, by, B2y);
        }
        Sx += fmaf(16.f, ax, B1x);
        Sy += fmaf(16.f, ay, B1y);
        SSx += fmaf(16.f*ax, ax, fmaf(2.f*ax, B1x, B2x));
        SSy += fmaf(16.f*ay, ay, fmaf(2.f*ay, B1y, B2y));
    }
    atomicAdd(&sstat[col],       Sx); atomicAdd(&sstat[col+1],       Sy);
    atomicAdd(&sstat[128 + col], SSx); atomicAdd(&sstat[128 + col+1], SSy);
    __syncthreads();
    if (t < 128) atomicAdd(&sums[t], sstat[t]);
    else         atomicAdd(&sumsq[t - 128], sstat[t]);
}

// --------- attn: h = qw[gp] + ew[nidx] formed inline from bf16 streams ->
// bn+relu -> sim(MFMA) -> softmax -> agg
__global__ __launch_bounds__(256) void k_attn3(
    const unsigned short* __restrict__ qw, const unsigned short* __restrict__ ew,
    const float* __restrict__ sums_h, const float* __restrict__ sumsq_h,
    const float* __restrict__ g1, const float* __restrict__ bt1,
    const unsigned short* __restrict__ W2sw,
    const unsigned short* __restrict__ v, const int* __restrict__ nidx,
    float* __restrict__ agg)
{
    __shared__ unsigned short WF[16384];
    __shared__ float s_sc[DS], s_sh[DS];
    const int t = threadIdx.x;
    #pragma unroll
    for (int i = 0; i < 8; i++)
        ((uint4*)WF)[t + 256*i] = ((const uint4*)W2sw)[t + 256*i];
    if (t < DS) {
        const float invM = 1.f / (float)MH;
        float m   = sums_h[t] * invM;
        float var = sumsq_h[t] * invM - m*m;
        float sc  = g1[t] * rsqrtf(var + 1e-5f);
        s_sc[t] = sc;
        s_sh[t] = bt1[t] - m * sc;
    }
    __syncthreads();

    const int w = t >> 6, lane = t & 63;
    const int gp = blockIdx.x * 4 + w;
    const int quad = lane >> 4, c = lane & 15;
    const int mrow = nidx[gp*16 + c];

    floatx4 acc[8];
    #pragma unroll
    for (int cj = 0; cj < 8; cj++) acc[cj] = (floatx4){0.f, 0.f, 0.f, 0.f};

    for (int ks = 0; ks < 4; ks++) {
        const int ko = ks*32 + quad*8;
        uint4 qv4 = *(const uint4*)(qw + (size_t)gp*DS + ko);
        uint4 ev4 = *(const uint4*)(ew + (size_t)mrow*DS + ko);
        floatx4 sc0 = *(const floatx4*)&s_sc[ko];
        floatx4 sc1 = *(const floatx4*)&s_sc[ko + 4];
        floatx4 sh0 = *(const floatx4*)&s_sh[ko];
        floatx4 sh1 = *(const floatx4*)&s_sh[ko + 4];
        unsigned qwv[4] = {qv4.x, qv4.y, qv4.z, qv4.w};
        unsigned ewv[4] = {ev4.x, ev4.y, ev4.z, ev4.w};
        short8 af;
        #pragma unroll
        for (int j = 0; j < 4; j++) {
            float h0 = bf2f((unsigned short)(qwv[j] & 0xffffu))
                     + bf2f((unsigned short)(ewv[j] & 0xffffu));
            float h1 = bf2f((unsigned short)(qwv[j] >> 16))
                     + bf2f((unsigned short)(ewv[j] >> 16));
            float f0 = fmaxf(fmaf(h0, (j<2)?sc0[2*j]:sc1[2*j-4],   (j<2)?sh0[2*j]:sh1[2*j-4]),   0.f);
            float f1 = fmaxf(fmaf(h1, (j<2)?sc0[2*j+1]:sc1[2*j-3], (j<2)?sh0[2*j+1]:sh1[2*j-3]), 0.f);
            ((unsigned*)&af)[j] = cvt_pk_bf16(f0, f1);
        }
        #pragma unroll
        for (int cj = 0; cj < 8; cj++) {
            short8 bfv = ((const short8*)WF)[(ks*8 + cj)*64 + lane];
            acc[cj] = __builtin_amdgcn_mfma_f32_16x16x32_bf16(af, bfv, acc[cj], 0, 0, 0);
        }
    }

    int nid[4];
    #pragma unroll
    for (int p = 0; p < 4; p++) nid[p] = nidx[gp*16 + quad*4 + p];

    #pragma unroll
    for (int cj = 0; cj < 8; cj++) {
        float m4 = fmaxf(fmaxf(acc[cj][0], acc[cj][1]), fmaxf(acc[cj][2], acc[cj][3]));
        m4 = fmaxf(m4, __shfl_xor(m4, 16));
        m4 = fmaxf(m4, __shfl_xor(m4, 32));
        float e[4]; float s4 = 0.f;
        #pragma unroll
        for (int p = 0; p < 4; p++) { e[p] = __expf(acc[cj][p] - m4); s4 += e[p]; }
        s4 += __shfl_xor(s4, 16); s4 += __shfl_xor(s4, 32);
        const float inv = 1.f / s4;
        const int col = cj*16 + c;
        float a = 0.f;
        #pragma unroll
        for (int p = 0; p < 4; p++)
            a = fmaf(e[p]*inv, bf2f(v[(size_t)nid[p]*DS + col]), a);
        a += __shfl_xor(a, 16); a += __shfl_xor(a, 32);
        if (quad == 0) agg[(size_t)gp*DS + col] = a;
    }
}

// bn+relu, float4-vectorized, inline finalize (memory-bound; output mlp only)
__global__ __launch_bounds__(256) void k_bnrelu(
    const float4* __restrict__ X, const float* __restrict__ sums,
    const float* __restrict__ sumsq, const float* __restrict__ g,
    const float* __restrict__ bt, float invM,
    float4* __restrict__ Y, size_t total4, int N)
{
    size_t i = (size_t)blockIdx.x * 256 + threadIdx.x;
    if (i < total4) {
        int c = (int)((i*4) & (size_t)(N - 1));
        float4 sm = *(const float4*)(sums + c);
        float4 sq = *(const float4*)(sumsq + c);
        float4 gg = *(const float4*)(g + c);
        float4 bb = *(const float4*)(bt + c);
        float4 x = X[i], y;
        float m0 = sm.x*invM, m1 = sm.y*invM, m2 = sm.z*invM, m3 = sm.w*invM;
        float s0 = gg.x*rsqrtf(sq.x*invM - m0*m0 + 1e-5f);
        float s1 = gg.y*rsqrtf(sq.y*invM - m1*m1 + 1e-5f);
        float s2 = gg.z*rsqrtf(sq.z*invM - m2*m2 + 1e-5f);
        float s3 = gg.w*rsqrtf(sq.w*invM - m3*m3 + 1e-5f);
        y.x = fmaxf(fmaf(x.x, s0, bb.x - m0*s0), 0.f);
        y.y = fmaxf(fmaf(x.y, s1, bb.y - m1*s1), 0.f);
        y.z = fmaxf(fmaf(x.z, s2, bb.z - m2*s2), 0.f);
        y.w = fmaxf(fmaf(x.w, s3, bb.w - m3*s3), 0.f);
        Y[i] = y;
    }
}

// ------- cooperative radix-select top-K, 2 queries/block (R14/R17/R23)
// R23: in-cap candidate POOL built during pass 1 (key,idx for bin<CAP);
// all mode-1 compactions scan the ~300-entry pool instead of re-scanning
// all NCAND candidates. kreg kept for refinement sub-histograms and the
// (rare) full-histogram fallback; pool overflow or fallback -> kreg rescan.
template<int NCAND, int KSEL, int EPI, int CAP>
__device__ __forceinline__ void sel_body(
    int gp0,
    const float4* __restrict__ qpts4, const float4* __restrict__ cpts4,
    const float* __restrict__ cpairs,
    int* __restrict__ nidx, const float* __restrict__ x2, float* __restrict__ xi,
    unsigned* hist0, unsigned* hist1,
    unsigned* skey, unsigned* sidx,          // [2*64] each
    unsigned* pkey, unsigned* pidxp,         // [2*POOLCAP] each (R23)
    float* swtE, unsigned* sidxE,            // [2*KSEL]
    unsigned* wpart, int* sstate)
{
    const int b = gp0 >> 12;
    const int t = threadIdx.x, wv = t >> 6, lane = t & 63;
    constexpr int ITER  = NCAND / 256;
    constexpr int PITER = NCAND / 512;

    const float4 qv0 = qpts4[gp0];
    const float4 qv1 = qpts4[gp0 + 1];
    const float4* pb = cpts4 + (size_t)b*NCAND;
    const float*  pbs = cpairs + (size_t)b*NCAND*4;

    unsigned kreg[2][ITER];
    if (t < 16)      ((uint4*)hist0)[t]      = (uint4){0u,0u,0u,0u};
    else if (t < 32) ((uint4*)hist1)[t - 16] = (uint4){0u,0u,0u,0u};
    if (t < 2) { sstate[t*8+5] = 0; sstate[t*8+6] = 0; }   // pool counters, fallback flags
    __syncthreads();

    {
        const float2v nqx0 = {-qv0.x, -qv0.x}, nqy0 = {-qv0.y, -qv0.y};
        const float2v nqz0 = {-qv0.z, -qv0.z}, qw0 = {qv0.w, qv0.w};
        const float2v nqx1 = {-qv1.x, -qv1.x}, nqy1 = {-qv1.y, -qv1.y};
        const float2v nqz1 = {-qv1.z, -qv1.z}, qw1 = {qv1.w, qv1.w};
        #pragma unroll
        for (int pi = 0; pi < PITER; pi++) {
            const int ip = t + 256*pi;
            float4 A  = ((const float4*)pbs)[2*ip];       // 2x0 2x1 2y0 2y1
            float4 Bv = ((const float4*)pbs)[2*ip + 1];   // 2z0 2z1 w0 w1
            float2v xp = {A.x, A.y},  yp = {A.z, A.w};
            float2v zp = {Bv.x, Bv.y}, wp = {Bv.z, Bv.w};
            float2v d0 = wp + qw0;
            d0 = __builtin_elementwise_fma(xp, nqx0, d0);
            d0 = __builtin_elementwise_fma(yp, nqy0, d0);
            d0 = __builtin_elementwise_fma(zp, nqz0, d0);
            float2v d1 = wp + qw1;
            d1 = __builtin_elementwise_fma(xp, nqx1, d1);
            d1 = __builtin_elementwise_fma(yp, nqy1, d1);
            d1 = __builtin_elementwise_fma(zp, nqz1, d1);
            unsigned kk[4];
            kk[0] = (unsigned)d0[0]; kk[1] = (unsigned)d0[1];
            kk[2] = (unsigned)d1[0]; kk[3] = (unsigned)d1[1];
            kreg[0][2*pi] = kk[0]; kreg[0][2*pi+1] = kk[1];
            kreg[1][2*pi] = kk[2]; kreg[1][2*pi+1] = kk[3];
            #pragma unroll
            for (int c2 = 0; c2 < 4; c2++) {
                const int qi = c2 >> 1;
                if ((kk[c2] >> 20) < CAP) {
                    atomicAdd((qi ? hist1 : hist0) + (kk[c2] >> 20), 1u);
                    int pp = (int)atomicAdd((unsigned*)&sstate[qi*8+5], 1u);
                    if (pp < POOLCAP) {
                        pkey[qi*POOLCAP + pp]  = kk[c2];
                        pidxp[qi*POOLCAP + pp] = (unsigned)(2*ip + (c2 & 1));
                    }
                }
            }
        }
    }
    __syncthreads();

    // single-wave threshold scan: wave 0 -> q0, wave 1 -> q1
    if (wv < 2) {
        unsigned* H = wv ? hist1 : hist0;
        unsigned h = (lane < CAP) ? H[lane] : 0u;
        unsigned incl = h;
        #pragma unroll
        for (int off = 1; off < 64; off <<= 1) {
            unsigned o = (unsigned)__shfl_up((int)incl, off);
            if (lane >= off) incl += o;
        }
        unsigned excl = incl - h;
        const int base = wv*8;
        if ((int)excl < KSEL && KSEL <= (int)(excl + h)) {
            sstate[base+0] = lane; sstate[base+1] = (int)excl; sstate[base+2] = (int)h;
            sstate[base+3] = ((int)(excl + h) <= 64) ? 1 : 0;
            sstate[base+4] = 0;
        }
        unsigned tot = (unsigned)__shfl((int)incl, 63);
        if (lane == 0 && (int)tot < KSEL) sstate[base+3] = -1;  // fallback flag
    }
    __syncthreads();

    // full-histogram fallback (rare; pool invalid for these queries)
    if (sstate[3] == -1 || sstate[11] == -1) {
        for (int qi = 0; qi < 2; qi++) {
            if (sstate[qi*8+3] != -1) continue;
            if (t == 0) sstate[qi*8+6] = 1;
            ((uint4*)hist0)[t] = (uint4){0u,0u,0u,0u};
            __syncthreads();
            #pragma unroll
            for (int it = 0; it < ITER; it++)
                atomicAdd(&hist0[kreg[qi][it] >> 20], 1u);
            __syncthreads();
            uint4 h4 = ((const uint4*)hist0)[t];
            unsigned hv[4] = {h4.x, h4.y, h4.z, h4.w};
            unsigned tsum = hv[0]+hv[1]+hv[2]+hv[3];
            unsigned incl = tsum;
            #pragma unroll
            for (int off = 1; off < 64; off <<= 1) {
                unsigned o = (unsigned)__shfl_up((int)incl, off);
                if (lane >= off) incl += o;
            }
            if (lane == 63) wpart[wv] = incl;
            __syncthreads();
            unsigned wbase = 0;
            for (int i2 = 0; i2 < wv; i2++) wbase += wpart[i2];
            unsigned excl = wbase + incl - tsum;
            if ((int)excl < KSEL && KSEL <= (int)(excl + tsum)) {
                unsigned cum = excl;
                #pragma unroll
                for (int i2 = 0; i2 < 4; i2++) {
                    unsigned h = hv[i2];
                    if ((int)cum < KSEL && KSEL <= (int)(cum + h)) {
                        sstate[qi*8+0] = t*4 + i2; sstate[qi*8+1] = (int)cum;
                        sstate[qi*8+2] = (int)h;
                        sstate[qi*8+3] = ((int)cum + (int)h <= 64) ? 1 : 0;
                        sstate[qi*8+4] = 0;
                        break;
                    }
                    cum += h;
                }
            }
            __syncthreads();
        }
    }

    // per-query: refinement (if needed) + compaction (pool-based when valid)
    #pragma unroll
    for (int qi = 0; qi < 2; qi++) {
        const float4 qv = qi ? qv1 : qv0;
        unsigned P = (unsigned)sstate[qi*8+0];
        int S = sstate[qi*8+1], cntB = sstate[qi*8+2], mode = sstate[qi*8+3];
        const bool usePool = (sstate[qi*8+6] == 0) && (sstate[qi*8+5] <= POOLCAP);
        int gsh = 20;
        if (mode == 0) {
            for (int round = 1; round < 4; round++) {
                const int nb  = (round == 3) ? 16 : 256;
                const int wb  = (round == 3) ? 4 : 8;
                const int sh  = (round == 1) ? 12 : (round == 2 ? 4 : 0);
                const int psh = sh + wb;
                if (t < nb) hist0[t] = 0u;
                __syncthreads();
                #pragma unroll
                for (int it = 0; it < ITER; it++) {
                    unsigned key = kreg[qi][it];
                    if ((key >> psh) == P)
                        atomicAdd(&hist0[(key >> sh) & (nb - 1)], 1u);
                }
                __syncthreads();
                unsigned hv = (t < nb) ? hist0[t] : 0u;
                unsigned tsum = hv;
                unsigned incl = tsum;
                #pragma unroll
                for (int off = 1; off < 64; off <<= 1) {
                    unsigned o = (unsigned)__shfl_up((int)incl, off);
                    if (lane >= off) incl += o;
                }
                if (lane == 63) wpart[wv] = incl;
                __syncthreads();
                unsigned wbase = 0;
                for (int i2 = 0; i2 < wv; i2++) wbase += wpart[i2];
                unsigned exclT = wbase + incl - tsum;
                const int need = KSEL - S;
                if ((int)exclT < need && need <= (int)(exclT + tsum)) {
                    int Snew = S + (int)exclT;
                    int tot  = Snew + (int)tsum;
                    sstate[qi*8+0] = (int)((P << wb) | (unsigned)t);
                    sstate[qi*8+1] = Snew; sstate[qi*8+2] = (int)tsum;
                    sstate[qi*8+3] = (tot <= 64) ? 1 : ((round == 3) ? 2 : 0);
                    sstate[qi*8+4] = 0;
                }
                __syncthreads();
                P = (unsigned)sstate[qi*8+0]; S = sstate[qi*8+1];
                cntB = sstate[qi*8+2]; mode = sstate[qi*8+3];
                gsh = sh;
                if (mode) break;
            }
        }
        if (mode == 1) {
            if (usePool) {
                const int pcnt = sstate[qi*8+5];
                for (int i = t; i < pcnt; i += 256) {
                    unsigned key = pkey[qi*POOLCAP + i];
                    if ((key >> gsh) <= P) {
                        int pos = (int)atomicAdd((unsigned*)&sstate[qi*8+4], 1u);
                        skey[qi*64 + pos] = key; sidx[qi*64 + pos] = pidxp[qi*POOLCAP + i];
                    }
                }
            } else {
                #pragma unroll
                for (int it = 0; it < ITER; it++) {
                    const int j = t + 256*((it & 1) ? (it >> 1) + PITER : (it >> 1));
                    // note: index mapping must match kreg layout: kreg[qi][it] holds
                    // candidate 2*(t+256*(it>>1)) + (it&1)
                    unsigned key = kreg[qi][it];
                    const int jj = 2*(t + 256*(it >> 1)) + (it & 1);
                    if ((key >> gsh) <= P) {
                        int pos = (int)atomicAdd((unsigned*)&sstate[qi*8+4], 1u);
                        skey[qi*64 + pos] = key; sidx[qi*64 + pos] = (unsigned)jj;
                    }
                }
            }
        } else if (mode == 2) {
            if (t < 64) {
                const unsigned long long lmask = (1ull << lane) - 1ull;
                int cnt = 0;
                for (int pass = 0; pass < 2; pass++) {
                    for (int it = 0; it < NCAND/64; it++) {
                        int j = lane + 64*it;
                        float4 cv = pb[j];
                        float dot = fmaf(qv.z, cv.z, fmaf(qv.y, cv.y, qv.x*cv.x));
                        float d2 = fmaxf(fmaf(-2.f, dot, qv.w + cv.w), 0.f);
                        unsigned key = (unsigned)d2;
                        bool f = pass ? (key == P) : (key < P);
                        unsigned long long bal = __ballot(f);
                        if (f) {
                            int pos = cnt + __popcll(bal & lmask);
                            if (pos < 64) { skey[qi*64 + pos] = key; sidx[qi*64 + pos] = (unsigned)j; }
                        }
                        cnt += __popcll(bal);
                    }
                }
                if (lane == 0) { sstate[qi*8+1] = min(cnt, 64); sstate[qi*8+2] = 0; }
            }
        }
        __syncthreads();
    }
    __syncthreads();

    if (wv < 2) {
        const int q = wv;
        const int total = sstate[q*8+1] + sstate[q*8+2];
        unsigned long long v = ~0ull;
        if (lane < total)
            v = (((unsigned long long)skey[q*64 + lane]) << 32) | sidx[q*64 + lane];
        #pragma unroll
        for (int k = 2; k <= 64; k <<= 1) {
            #pragma unroll
            for (int jj = k >> 1; jj > 0; jj >>= 1) {
                unsigned long long p = shfl_xor_u64(v, jj);
                bool up = ((lane & k) == 0);
                bool takeMin = (((lane & jj) == 0) == up);
                bool pl = p < v;
                v = (takeMin == pl) ? p : v;
            }
        }
        if (EPI == 0) {
            if (lane < KSEL)
                nidx[(gp0 + q)*KSEL + lane] = b*NCAND + (int)(v & 0xffffffffull);
        } else {
            const float4 qq = q ? qv1 : qv0;
            float wgt = 0.f;
            unsigned si = (unsigned)(v & 0xffffffffull);
            if (lane < KSEL) {
                float4 cv = pb[si];
                float dot = fmaf(qq.z, cv.z, fmaf(qq.y, cv.y, qq.x*cv.x));
                float d2 = fmaxf(fmaf(-2.f, dot, qq.w + cv.w), 0.f);
                // d2 is scaled by 2^28; 1e-8 * 2^14 = 1.6384e-4; the 2^14 factor
                // cancels in the weight normalization below
                wgt = 1.f / (sqrtf(d2) + 1.6384e-4f);
            }
            float ws = wgt;
            ws += __shfl_xor(ws, 1); ws += __shfl_xor(ws, 2); ws += __shfl_xor(ws, 4);
            if (lane < KSEL) {
                swtE[q*KSEL + lane]  = wgt / ws;
                sidxE[q*KSEL + lane] = si;
            }
        }
    }

    if (EPI == 1) {
        __syncthreads();
        const int qi2 = t >> 7, tt = t & 127;
        const float* x2b = x2 + (size_t)b*NCAND*DS;
        float a = 0.f;
        #pragma unroll
        for (int r = 0; r < KSEL; r++)
            a = fmaf(swtE[qi2*KSEL + r], x2b[(size_t)sidxE[qi2*KSEL + r]*DS + tt], a);
        xi[(size_t)(gp0 + qi2)*DS + tt] = a;
    }
}

__global__ __launch_bounds__(256) void k_sel2(
    const float4* __restrict__ p1q, const float4* __restrict__ p2q,
    const float* __restrict__ p1s, const float* __restrict__ p2s,
    int* __restrict__ nidx, const float* __restrict__ x2, float* __restrict__ xi)
{
    __shared__ __align__(16) unsigned hist0[1024], hist1[1024];
    __shared__ __align__(16) unsigned skey[128], sidx[128];
    __shared__ __align__(16) unsigned pkey[2*POOLCAP], pidxp[2*POOLCAP];
    __shared__ float    swtE[2*KI];
    __shared__ unsigned sidxE[2*KI];
    __shared__ unsigned wpart[8];
    __shared__ int      sstate[20];
    const int bid = blockIdx.x;
    if (bid < M1/2) {
        // kNN-16: p1 vs p1, 4096 candidates; CAP=16 (d^2<0.0625 scaled)
        sel_body<NN1, KN, 0, 16>(bid*2, p1q, p1q, p1s, nidx, nullptr, nullptr,
                                 hist0, hist1, skey, sidx, pkey, pidxp,
                                 swtE, sidxE, wpart, sstate);
    } else {
        // interp-8: p1 vs p2, 1024 candidates + gather epilogue; CAP=32
        sel_body<NN2, KI, 1, 32>((bid - M1/2)*2, p1q, p2q, p2s, nullptr, x2, xi,
                                 hist0, hist1, skey, sidx, pkey, pidxp,
                                 swtE, sidxE, wpart, sstate);
    }
}

// ---------------------------------------------------------------- launch
extern "C" void kernel_launch(void* const* d_in, const int* in_sizes, int n_in,
                              void* d_out, int out_size, void* d_ws, size_t ws_size,
                              hipStream_t stream)
{
    const float* p1 = (const float*)d_in[0];
    const float* x1 = (const float*)d_in[1];
    const int*   o1 = (const int*)d_in[2];
    const float* p2 = (const float*)d_in[3];
    const float* x2 = (const float*)d_in[4];
    const float* W_dense = (const float*)d_in[7];
    const float* b_dense = (const float*)d_in[8];
    const float* g_dense = (const float*)d_in[9];
    const float* bt_dense= (const float*)d_in[10];
    const float* Wq = (const float*)d_in[11];
    const float* Wk = (const float*)d_in[12];
    const float* Wv = (const float*)d_in[13];
    const float* W1 = (const float*)d_in[14];
    const float* b1 = (const float*)d_in[15];
    const float* g1 = (const float*)d_in[16];
    const float* bt1= (const float*)d_in[17];
    const float* W2 = (const float*)d_in[18];
    const float* W_out = (const float*)d_in[20];
    const float* b_out = (const float*)d_in[21];
    const float* g_out = (const float*)d_in[22];
    const float* bt_out= (const float*)d_in[23];

    float* ws   = (float*)d_ws;
    unsigned short* wts  = (unsigned short*)(ws + OFF_WTS);
    float* tmp  = ws + OFF_TMP;
    float* xi   = ws + OFF_XI;
    float* qm   = ws + OFF_Q;
    float* outp = ws + OFF_OUTP;
    int*   nidx = (int*)(ws + OFF_NIDX);
    float* stat = ws + OFF_STAT;
    float4* p1q = (float4*)(ws + OFF_P1Q);
    float4* p2q = (float4*)(ws + OFF_P2Q);
    float* p1s = ws + OFF_P1S;
    float* p2s = ws + OFF_P2S;
    unsigned short* q16 = (unsigned short*)(ws + OFF_Q);
    unsigned short* e16 = (unsigned short*)(ws + OFF_K);
    unsigned short* v16 = (unsigned short*)(ws + OFF_V);
    unsigned short* qw16 = (unsigned short*)(ws + OFF_XD);
    unsigned short* ew16 = (unsigned short*)(ws + OFF_OUTP);
    float* sums_d = stat,      *sumsq_d = stat+256;
    float* sums_h = stat+1024, *sumsq_h = stat+1280;
    float* sums_o = stat+2048, *sumsq_o = stat+2304;
    float* out = (float*)d_out;

    // prolog + weight swizzles, one launch
    SwzParams sp;
    sp.W[0]=W_dense; sp.W[1]=Wq; sp.W[2]=Wk; sp.W[3]=Wv; sp.W[4]=W1; sp.W[5]=W2; sp.W[6]=W_out;
    sp.hi[0]=wts+WDH; sp.hi[1]=wts+WQH; sp.hi[2]=wts+WKH; sp.hi[3]=wts+WVH;
    sp.hi[4]=wts+W1H; sp.hi[5]=wts+W2H; sp.hi[6]=wts+WOH;
    sp.lo[0]=wts+WDL; sp.lo[1]=wts+WQL; sp.lo[2]=wts+WKL; sp.lo[3]=wts+WVL;
    sp.lo[4]=wts+W1L; sp.lo[5]=wts+W2L; sp.lo[6]=wts+WOL;
    sp.N[0]=128; sp.N[1]=128; sp.N[2]=128; sp.N[3]=128; sp.N[4]=128; sp.N[5]=128; sp.N[6]=256;
    sp.fid0[0]=0; sp.fid0[1]=16; sp.fid0[2]=48; sp.fid0[3]=80; sp.fid0[4]=112;
    sp.fid0[5]=144; sp.fid0[6]=176; sp.fid0[7]=272;
    k_prolog<<<NPRO + 68, 256, 0, stream>>>(p1, o1, p2, out, stat, p1q, p2q, p1s, p2s, sp);

    // both top-K selects (kNN-16 + interp-8 with gather epilogue), one launch
    k_sel2<<<M1, 256, 0, stream>>>(p1q, p2q, p1s, p2s, nidx, x2, xi);

    // dense_mlp GEMM (stats fused, N-split x2); bn+relu applied downstream
    k_gemm_mf<128,64,0,1,0,2><<<dim3(M1/64,2), 256, 0, stream>>>(x1, wts+WDH, wts+WDL,
        b_dense, tmp, nullptr, sums_d, sumsq_d, nullptr, nullptr, nullptr, nullptr);

    // q, k, v projections — one launch (y=seg, z=N-split x4); BN(dense) fused;
    // bf16 outputs: q / e=xd-k / v2=v+xd
    k_gemm_mf<128,128,3,0,1,4><<<dim3(M1/64,3,4), 256, 0, stream>>>(tmp, wts+WQH, wts+WQL,
        nullptr, qm, xi, nullptr, nullptr, sums_d, sumsq_d, g_dense, bt_dense);

    // h@W1 = q@W1 + e@W1 (MFMA linearity) — bf16 GEMMs (y=q/e, z=N-split x4)
    k_gemm_qe<<<dim3(M1/64, 2, 4), 256, 0, stream>>>(q16, e16, wts+W1H, b1, qw16, ew16);
    // BN stats over h computed WITHOUT materializing h (bf16 streams)
    k_hstat<<<M1/16, 256, 0, stream>>>(qw16, ew16, nidx, sums_h, sumsq_h);

    // attn: h formed inline from bf16 qw/ew, BN finalize inline, bf16 v2
    k_attn3<<<M1/4, 256, 0, stream>>>(qw16, ew16, sums_h, sumsq_h, g1, bt1,
        wts+W2H, v16, nidx, tmp);

    // output mlp (stats fused, N-split x8) -> bn+relu (finalize inline, float4)
    k_gemm_mf<256,192,2,1,0,8><<<dim3(M1/64,8), 256, 0, stream>>>(tmp, wts+WOH, wts+WOL,
        b_out, outp, x1, sums_o, sumsq_o, nullptr, nullptr, nullptr, nullptr);
    k_bnrelu<<<(M1*DOUT/4)/256, 256, 0, stream>>>((const float4*)outp, sums_o, sumsq_o,
        g_out, bt_out, 1.f/(float)M1, (float4*)(out + OUT_X), (size_t)M1*DOUT/4, DOUT);
}

// Round 12
// 296.644 us; speedup vs baseline: 1.0867x; 1.0867x over previous
//
#include <hip/hip_runtime.h>
#include <math.h>

#define BB 4
#define NN1 4096
#define NN2 1024
#define DS 128
#define DD 64
#define DOUT 256
#define M1 16384        // BB*NN1
#define MH 262144       // M1*16
#define KCAT 192        // DS+DD
#define KI 8            // interp k
#define KN 16           // neighbor k

#define OUT_P1 49152
#define OUT_X  49152
#define OUT_O1 4243456

// coordinates pre-scaled by 2^14 in prolog -> d^2 is directly the 2^28 fixed-point key
// pair-SoA additionally stores 2*x,2*y,2*z so d^2 = (qn+cn) - x2*qx - y2*qy - z2*qz

// ---- workspace layout (float offsets) ----
static const size_t OFF_WTS  = 16777216;               // swizzled weights (hi/lo)
static const size_t OFF_TMP  = 33554432;
static const size_t OFF_XD   = OFF_TMP  + 2097152;     // bf16 qw (M1*128)
static const size_t OFF_XI   = OFF_XD   + 2097152;
static const size_t OFF_Q    = OFF_XI   + 2097152;     // bf16 q
static const size_t OFF_K    = OFF_Q    + 2097152;     // bf16 e = xd - k
static const size_t OFF_V    = OFF_K    + 2097152;     // bf16 v2 = v + xd
static const size_t OFF_OUTP = OFF_V    + 2097152;     // bf16 ew (then out-mlp C f32)
static const size_t OFF_NIDX = OFF_OUTP + 4194304;
static const size_t OFF_STAT = OFF_NIDX + 262144;      // 3072 floats
static const size_t OFF_P1Q  = OFF_STAT + 4096;        // 16384 float4 (AoS, scaled)
static const size_t OFF_P2Q  = OFF_P1Q  + 65536;       // 4096 float4 (AoS, scaled)
static const size_t OFF_P1S  = OFF_P2Q  + 16384;       // pair-SoA p1 (65536 floats)
static const size_t OFF_P2S  = OFF_P1S  + 65536;       // pair-SoA p2 (16384 floats)

// ushort offsets inside the weights region
#define WDH 0
#define WDL 8192
#define WQH 16384
#define WQL 32768
#define WKH 49152
#define WKL 65536
#define WVH 81920
#define WVL 98304
#define W1H 114688
#define W1L 131072
#define W2H 147456
#define W2L 163840
#define WOH 180224
#define WOL 229376

typedef __attribute__((ext_vector_type(8))) short short8;
typedef __attribute__((ext_vector_type(4))) float floatx4;
typedef __attribute__((ext_vector_type(2))) float float2v;

__device__ inline unsigned short f2bf(float f) {
    union { float f; unsigned int u; } x; x.f = f;
    unsigned int r = x.u + 0x7fffu + ((x.u >> 16) & 1u);
    return (unsigned short)(r >> 16);
}
__device__ inline float bf2f(unsigned short h) {
    union { unsigned int u; float f; } x; x.u = ((unsigned int)h) << 16;
    return x.f;
}
__device__ inline unsigned long long shfl_xor_u64(unsigned long long v, int m) {
    unsigned lo = (unsigned)v, hi = (unsigned)(v >> 32);
    lo = (unsigned)__shfl_xor((int)lo, m);
    hi = (unsigned)__shfl_xor((int)hi, m);
    return ((unsigned long long)hi << 32) | lo;
}
// 2×f32 -> packed 2×bf16 (RNE; matches f2bf)
__device__ inline unsigned cvt_pk_bf16(float lo, float hi) {
    unsigned r;
    asm volatile("v_cvt_pk_bf16_f32 %0, %1, %2" : "=v"(r) : "v"(lo), "v"(hi));
    return r;
}

// --------- prolog + swizzle merged: copyout, stat zero, point pack, W swizzle
#define PRO_STAT  (OUT_P1 + BB)          // 49156
#define PRO_PACK  (PRO_STAT + 3072)      // 52228
#define PRO_TOTAL (PRO_PACK + M1 + BB*NN2)   // 72708
#define NPRO 285
struct SwzParams {
    const float* W[7];
    unsigned short* hi[7];
    unsigned short* lo[7];
    int N[7];
    int fid0[8];
};
__global__ __launch_bounds__(256) void k_prolog(
    const float* __restrict__ p1, const int* __restrict__ o1,
    const float* __restrict__ p2, float* __restrict__ out,
    float* __restrict__ stat, float4* __restrict__ p1q,
    float4* __restrict__ p2q, float* __restrict__ p1s,
    float* __restrict__ p2s, SwzParams p)
{
    if (blockIdx.x < NPRO) {
        int i = blockIdx.x * 256 + threadIdx.x;
        if (i < OUT_P1) out[i] = p1[i];
        else if (i < PRO_STAT) out[OUT_O1 + (i - OUT_P1)] = (float)o1[i - OUT_P1];
        else if (i < PRO_PACK) stat[i - PRO_STAT] = 0.f;
        else if (i < PRO_TOTAL) {
            int j = i - PRO_PACK;
            const float* src; float4* dst; float* ps; int jj;
            if (j < M1) { src = p1; dst = p1q; ps = p1s; jj = j; }
            else        { src = p2; dst = p2q; ps = p2s; jj = j - M1; }
            // scale by 2^14 (exact): d^2 in scaled space == 2^28 fixed-point key
            float x = src[jj*3+0] * 16384.f;
            float y = src[jj*3+1] * 16384.f;
            float z = src[jj*3+2] * 16384.f;
            float n = fmaf(z, z, fmaf(y, y, x*x));
            dst[jj] = make_float4(x, y, z, n);
            int pb8 = (jj >> 1)*8 + (jj & 1);   // pair-SoA: 2x0 2x1 2y0 2y1 2z0 2z1 w0 w1
            ps[pb8]   = x + x; ps[pb8+2] = y + y;
            ps[pb8+4] = z + z; ps[pb8+6] = n;
        }
        return;
    }
    int fid = (blockIdx.x - NPRO)*4 + (threadIdx.x >> 6);
    int lane = threadIdx.x & 63;
    if (fid >= 272) return;
    int seg = 0;
    #pragma unroll
    for (int i = 1; i < 7; i++) if (fid >= p.fid0[i]) seg = i;
    int f = fid - p.fid0[seg];
    const float* W = p.W[seg];
    int N = p.N[seg];
    int ncj = N >> 4;
    int slab = f / ncj, cj = f - slab*ncj;
    int n  = cj*16 + (lane & 15);
    int k0 = slab*32 + (lane >> 4)*8;
    unsigned int oh[8], ol[8];
    #pragma unroll
    for (int j = 0; j < 8; j++) {
        float v = W[(size_t)(k0 + j) * N + n];
        unsigned short h = f2bf(v);
        oh[j] = h;
        ol[j] = f2bf(v - bf2f(h));
    }
    uint4 ph, pl;
    ph.x = oh[0] | (oh[1] << 16); ph.y = oh[2] | (oh[3] << 16);
    ph.z = oh[4] | (oh[5] << 16); ph.w = oh[6] | (oh[7] << 16);
    pl.x = ol[0] | (ol[1] << 16); pl.y = ol[2] | (ol[3] << 16);
    pl.z = ol[4] | (ol[5] << 16); pl.w = ol[6] | (ol[7] << 16);
    ((uint4*)p.hi[seg])[f*64 + lane] = ph;
    ((uint4*)p.lo[seg])[f*64 + lane] = pl;
}

// ----------------------------- split-bf16 MFMA GEMM (near-fp32 via hi/lo x 3)
// MODE 0: A plain. MODE 2: A = concat(Amat, aux). MODE 3: qkv, bf16 out —
//   seg0: q = bn(tmp)@Wq ; seg1: e = bn(tmp) - xi@Wk ; seg2: v2 = xi@Wv + bn(tmp).
// NSPL: N-dimension split — each block computes ncj/NSPL col-groups.
template<int N, int K, int MODE, int STATS, int BNA, int NSPL>
__global__ __launch_bounds__(256) void k_gemm_mf(
    const float* __restrict__ Amat, const unsigned short* __restrict__ Whi,
    const unsigned short* __restrict__ Wlo, const float* __restrict__ bias,
    float* __restrict__ C, const float* __restrict__ aux,
    float* __restrict__ sums, float* __restrict__ sumsq,
    const float* __restrict__ bsums, const float* __restrict__ bsumsq,
    const float* __restrict__ bg, const float* __restrict__ bbt)
{
    constexpr int ncj  = N >> 4;
    constexpr int ncjL = ncj / NSPL;     // col-groups per block
    constexpr int NL   = ncjL * 16;      // cols per block
    __shared__ float sstat[STATS ? 2*NL : 1];
    __shared__ float sbn[BNA ? 2*DS : 1];
    const int t = threadIdx.x, w = t >> 6, lane = t & 63;
    const int quad = lane >> 4, c = lane & 15;
    const int row = blockIdx.x*64 + w*16 + c;
    const int sA = (MODE == 2) ? DS : K;
    constexpr int nslab = K >> 5;
    const int seg = (MODE == 3) ? blockIdx.y : 0;
    const int yn  = (MODE == 3) ? blockIdx.z : blockIdx.y;
    const int cj0 = yn * ncjL;
    const float* Abase = (MODE == 3 && seg > 0) ? aux : Amat;
    const unsigned short* WhiS = Whi + (size_t)seg*32768;
    const unsigned short* WloS = Wlo + (size_t)seg*32768;
    float* CS = C + (size_t)seg*2097152;
    unsigned short* CS16 = (unsigned short*)C + (size_t)seg*4194304;
    if (STATS) {
        for (int i = t; i < 2*NL; i += 256) sstat[i] = 0.f;
    }
    if (BNA) {
        if (t < DS) {
            const float invM = 1.f / (float)M1;
            float m   = bsums[t] * invM;
            float var = bsumsq[t] * invM - m*m;
            float sc  = bg[t] * rsqrtf(var + 1e-5f);
            sbn[t] = sc;
            sbn[DS + t] = bbt[t] - m * sc;
        }
    }
    if (STATS || BNA) __syncthreads();

    floatx4 acc[ncjL];
    #pragma unroll
    for (int cj = 0; cj < ncjL; cj++) acc[cj] = (floatx4){0.f,0.f,0.f,0.f};

    #pragma unroll
    for (int slab = 0; slab < nslab; slab++) {
        const int kk = slab*32 + quad*8;
        const float* src;
        if (MODE == 2 && kk >= DS) src = aux + (size_t)row*DD + (kk - DS);
        else                       src = Abase + (size_t)row*sA + kk;
        floatx4 va = *(const floatx4*)src;
        floatx4 vb = *(const floatx4*)(src + 4);
        if (BNA && MODE == 3 && seg == 0) {
            #pragma unroll
            for (int j = 0; j < 4; j++) {
                va[j] = fmaxf(fmaf(va[j], sbn[kk+j],   sbn[DS+kk+j]),   0.f);
                vb[j] = fmaxf(fmaf(vb[j], sbn[kk+4+j], sbn[DS+kk+4+j]), 0.f);
            }
        }
        short8 ahi, alo;
        #pragma unroll
        for (int j = 0; j < 4; j++) {
            unsigned short h = f2bf(va[j]);
            ahi[j] = (short)h; alo[j] = (short)f2bf(va[j] - bf2f(h));
        }
        #pragma unroll
        for (int j = 0; j < 4; j++) {
            unsigned short h = f2bf(vb[j]);
            ahi[4+j] = (short)h; alo[4+j] = (short)f2bf(vb[j] - bf2f(h));
        }
        const short8* bh = (const short8*)WhiS + (size_t)slab*ncj*64;
        const short8* bl = (const short8*)WloS + (size_t)slab*ncj*64;
        #pragma unroll
        for (int cj = 0; cj < ncjL; cj++) {
            short8 bhv = bh[(cj0 + cj)*64 + lane];
            short8 blv = bl[(cj0 + cj)*64 + lane];
            acc[cj] = __builtin_amdgcn_mfma_f32_16x16x32_bf16(alo, bhv, acc[cj], 0, 0, 0);
            acc[cj] = __builtin_amdgcn_mfma_f32_16x16x32_bf16(ahi, blv, acc[cj], 0, 0, 0);
            acc[cj] = __builtin_amdgcn_mfma_f32_16x16x32_bf16(ahi, bhv, acc[cj], 0, 0, 0);
        }
    }
    const int rbase = blockIdx.x*64 + w*16 + quad*4;
    #pragma unroll
    for (int cj = 0; cj < ncjL; cj++) {
        const int colG = (cj0 + cj)*16 + c;
        const float bb = bias ? bias[colG] : 0.f;
        float s = 0.f, ss = 0.f;
        #pragma unroll
        for (int p = 0; p < 4; p++) {
            float v = acc[cj][p] + bb;
            if (MODE == 3) {
                if (seg > 0) {
                    float xv = Amat[(size_t)(rbase + p)*DS + colG];
                    if (BNA) xv = fmaxf(fmaf(xv, sbn[colG], sbn[DS+colG]), 0.f);
                    if (seg == 1) v = xv - v;     // e = xd - k
                    else          v += xv;        // v2 = v + xd
                }
                CS16[(size_t)(rbase + p)*N + colG] = f2bf(v);
            } else {
                CS[(size_t)(rbase + p)*N + colG] = v;
            }
            if (STATS) { s += v; ss += v*v; }
        }
        if (STATS) {
            s  += __shfl_xor(s, 16);  s  += __shfl_xor(s, 32);
            ss += __shfl_xor(ss, 16); ss += __shfl_xor(ss, 32);
            if (quad == 0) {
                atomicAdd(&sstat[cj*16 + c], s);
                atomicAdd(&sstat[NL + cj*16 + c], ss);
            }
        }
    }
    if (STATS) {
        __syncthreads();
        for (int i = t; i < NL; i += 256) {
            atomicAdd(&sums[cj0*16 + i],  sstat[i]);
            atomicAdd(&sumsq[cj0*16 + i], sstat[NL + i]);
        }
    }
}

// -------------------- qW1 / eW1 dense bf16 GEMMs (h = q+e linearity), bf16 out
// y==0: qw = q16 @ W1hi ; y==1: ew = e16 @ W1hi + b1.  z: N-split x2.
__global__ __launch_bounds__(256) void k_gemm_qe(
    const unsigned short* __restrict__ q16, const unsigned short* __restrict__ e16,
    const unsigned short* __restrict__ W1hi, const float* __restrict__ b1,
    unsigned short* __restrict__ qw, unsigned short* __restrict__ ew)
{
    const int t = threadIdx.x, w = t >> 6, lane = t & 63;
    const int quad = lane >> 4, c = lane & 15;
    const int y = blockIdx.y;
    const int cj0 = blockIdx.z * 4;
    const unsigned short* A = y ? e16 : q16;
    unsigned short* C16 = y ? ew : qw;
    const int row = blockIdx.x*64 + w*16 + c;

    floatx4 acc[4];
    #pragma unroll
    for (int cj = 0; cj < 4; cj++) acc[cj] = (floatx4){0.f,0.f,0.f,0.f};

    #pragma unroll
    for (int slab = 0; slab < 4; slab++) {
        uint4 av = *(const uint4*)(A + (size_t)row*DS + slab*32 + quad*8);
        short8 af;
        ((uint4*)&af)[0] = av;
        const short8* bh = (const short8*)W1hi + (size_t)slab*8*64;
        #pragma unroll
        for (int cj = 0; cj < 4; cj++) {
            short8 bhv = bh[(cj0 + cj)*64 + lane];
            acc[cj] = __builtin_amdgcn_mfma_f32_16x16x32_bf16(af, bhv, acc[cj], 0, 0, 0);
        }
    }
    const int rbase = blockIdx.x*64 + w*16 + quad*4;
    #pragma unroll
    for (int cj = 0; cj < 4; cj++) {
        const int colG = (cj0 + cj)*16 + c;
        const float bb = y ? b1[colG] : 0.f;
        #pragma unroll
        for (int p = 0; p < 4; p++)
            C16[(size_t)(rbase + p)*DS + colG] = f2bf(acc[cj][p] + bb);
    }
}

// -------------------- BN stats over h WITHOUT materializing h (bf16 streams)
// per gp (query): sum_c (a+b_c) = 16a + B1 ; sum_c (a+b_c)^2 = 16a^2 + 2a*B1 + B2
__global__ __launch_bounds__(256) void k_hstat(
    const unsigned short* __restrict__ qw, const unsigned short* __restrict__ ew,
    const int* __restrict__ nidx,
    float* __restrict__ sums, float* __restrict__ sumsq)
{
    __shared__ float sstat[256];
    const int t = threadIdx.x, w = t >> 6, lane = t & 63;
    sstat[t] = 0.f;
    __syncthreads();
    const int col = lane*2;
    float Sx = 0.f, Sy = 0.f, SSx = 0.f, SSy = 0.f;
    #pragma unroll
    for (int g2 = 0; g2 < 4; g2++) {
        const int gp = blockIdx.x*16 + w*4 + g2;
        unsigned av = *(const unsigned*)(qw + (size_t)gp*DS + col);
        float ax = bf2f((unsigned short)(av & 0xffffu));
        float ay = bf2f((unsigned short)(av >> 16));
        float B1x = 0.f, B1y = 0.f, B2x = 0.f, B2y = 0.f;
        const int* np = nidx + gp*16;
        #pragma unroll
        for (int cc = 0; cc < 16; cc++) {
            int m = np[cc];
            unsigned bv = *(const unsigned*)(ew + (size_t)m*DS + col);
            float bx = bf2f((unsigned short)(bv & 0xffffu));
            float by = bf2f((unsigned short)(bv >> 16));
            B1x += bx; B1y += by;
            B2x = fmaf(bx, bx, B2x); B2y = fmaf(by, by, B2y);
        }
        Sx += fmaf(16.f, ax, B1x);
        Sy += fmaf(16.f, ay, B1y);
        SSx += fmaf(16.f*ax, ax, fmaf(2.f*ax, B1x, B2x));
        SSy += fmaf(16.f*ay, ay, fmaf(2.f*ay, B1y, B2y));
    }
    atomicAdd(&sstat[col],       Sx); atomicAdd(&sstat[col+1],       Sy);
    atomicAdd(&sstat[128 + col], SSx); atomicAdd(&sstat[128 + col+1], SSy);
    __syncthreads();
    if (t < 128) atomicAdd(&sums[t], sstat[t]);
    else         atomicAdd(&sumsq[t - 128], sstat[t]);
}

// --------- attn: h = qw[gp] + ew[nidx] formed inline from bf16 streams ->
// bn+relu -> sim(MFMA) -> softmax -> agg
__global__ __launch_bounds__(256) void k_attn3(
    const unsigned short* __restrict__ qw, const unsigned short* __restrict__ ew,
    const float* __restrict__ sums_h, const float* __restrict__ sumsq_h,
    const float* __restrict__ g1, const float* __restrict__ bt1,
    const unsigned short* __restrict__ W2sw,
    const unsigned short* __restrict__ v, const int* __restrict__ nidx,
    float* __restrict__ agg)
{
    __shared__ unsigned short WF[16384];
    __shared__ float s_sc[DS], s_sh[DS];
    const int t = threadIdx.x;
    #pragma unroll
    for (int i = 0; i < 8; i++)
        ((uint4*)WF)[t + 256*i] = ((const uint4*)W2sw)[t + 256*i];
    if (t < DS) {
        const float invM = 1.f / (float)MH;
        float m   = sums_h[t] * invM;
        float var = sumsq_h[t] * invM - m*m;
        float sc  = g1[t] * rsqrtf(var + 1e-5f);
        s_sc[t] = sc;
        s_sh[t] = bt1[t] - m * sc;
    }
    __syncthreads();

    const int w = t >> 6, lane = t & 63;
    const int gp = blockIdx.x * 4 + w;
    const int quad = lane >> 4, c = lane & 15;
    const int mrow = nidx[gp*16 + c];

    floatx4 acc[8];
    #pragma unroll
    for (int cj = 0; cj < 8; cj++) acc[cj] = (floatx4){0.f, 0.f, 0.f, 0.f};

    for (int ks = 0; ks < 4; ks++) {
        const int ko = ks*32 + quad*8;
        uint4 qv4 = *(const uint4*)(qw + (size_t)gp*DS + ko);
        uint4 ev4 = *(const uint4*)(ew + (size_t)mrow*DS + ko);
        floatx4 sc0 = *(const floatx4*)&s_sc[ko];
        floatx4 sc1 = *(const floatx4*)&s_sc[ko + 4];
        floatx4 sh0 = *(const floatx4*)&s_sh[ko];
        floatx4 sh1 = *(const floatx4*)&s_sh[ko + 4];
        unsigned qwv[4] = {qv4.x, qv4.y, qv4.z, qv4.w};
        unsigned ewv[4] = {ev4.x, ev4.y, ev4.z, ev4.w};
        short8 af;
        #pragma unroll
        for (int j = 0; j < 4; j++) {
            float h0 = bf2f((unsigned short)(qwv[j] & 0xffffu))
                     + bf2f((unsigned short)(ewv[j] & 0xffffu));
            float h1 = bf2f((unsigned short)(qwv[j] >> 16))
                     + bf2f((unsigned short)(ewv[j] >> 16));
            float f0 = fmaxf(fmaf(h0, (j<2)?sc0[2*j]:sc1[2*j-4],   (j<2)?sh0[2*j]:sh1[2*j-4]),   0.f);
            float f1 = fmaxf(fmaf(h1, (j<2)?sc0[2*j+1]:sc1[2*j-3], (j<2)?sh0[2*j+1]:sh1[2*j-3]), 0.f);
            ((unsigned*)&af)[j] = cvt_pk_bf16(f0, f1);
        }
        #pragma unroll
        for (int cj = 0; cj < 8; cj++) {
            short8 bfv = ((const short8*)WF)[(ks*8 + cj)*64 + lane];
            acc[cj] = __builtin_amdgcn_mfma_f32_16x16x32_bf16(af, bfv, acc[cj], 0, 0, 0);
        }
    }

    int nid[4];
    #pragma unroll
    for (int p = 0; p < 4; p++) nid[p] = nidx[gp*16 + quad*4 + p];

    #pragma unroll
    for (int cj = 0; cj < 8; cj++) {
        float m4 = fmaxf(fmaxf(acc[cj][0], acc[cj][1]), fmaxf(acc[cj][2], acc[cj][3]));
        m4 = fmaxf(m4, __shfl_xor(m4, 16));
        m4 = fmaxf(m4, __shfl_xor(m4, 32));
        float e[4]; float s4 = 0.f;
        #pragma unroll
        for (int p = 0; p < 4; p++) { e[p] = __expf(acc[cj][p] - m4); s4 += e[p]; }
        s4 += __shfl_xor(s4, 16); s4 += __shfl_xor(s4, 32);
        const float inv = 1.f / s4;
        const int col = cj*16 + c;
        float a = 0.f;
        #pragma unroll
        for (int p = 0; p < 4; p++)
            a = fmaf(e[p]*inv, bf2f(v[(size_t)nid[p]*DS + col]), a);
        a += __shfl_xor(a, 16); a += __shfl_xor(a, 32);
        if (quad == 0) agg[(size_t)gp*DS + col] = a;
    }
}

// bn+relu, float4-vectorized, inline finalize (memory-bound; output mlp only)
__global__ __launch_bounds__(256) void k_bnrelu(
    const float4* __restrict__ X, const float* __restrict__ sums,
    const float* __restrict__ sumsq, const float* __restrict__ g,
    const float* __restrict__ bt, float invM,
    float4* __restrict__ Y, size_t total4, int N)
{
    size_t i = (size_t)blockIdx.x * 256 + threadIdx.x;
    if (i < total4) {
        int c = (int)((i*4) & (size_t)(N - 1));
        float4 sm = *(const float4*)(sums + c);
        float4 sq = *(const float4*)(sumsq + c);
        float4 gg = *(const float4*)(g + c);
        float4 bb = *(const float4*)(bt + c);
        float4 x = X[i], y;
        float m0 = sm.x*invM, m1 = sm.y*invM, m2 = sm.z*invM, m3 = sm.w*invM;
        float s0 = gg.x*rsqrtf(sq.x*invM - m0*m0 + 1e-5f);
        float s1 = gg.y*rsqrtf(sq.y*invM - m1*m1 + 1e-5f);
        float s2 = gg.z*rsqrtf(sq.z*invM - m2*m2 + 1e-5f);
        float s3 = gg.w*rsqrtf(sq.w*invM - m3*m3 + 1e-5f);
        y.x = fmaxf(fmaf(x.x, s0, bb.x - m0*s0), 0.f);
        y.y = fmaxf(fmaf(x.y, s1, bb.y - m1*s1), 0.f);
        y.z = fmaxf(fmaf(x.z, s2, bb.z - m2*s2), 0.f);
        y.w = fmaxf(fmaf(x.w, s3, bb.w - m3*s3), 0.f);
        Y[i] = y;
    }
}

// ------- cooperative radix-select top-K, 2 queries/block (R14/R17)
// capped pass-1 histogram + single-wave threshold scan + pair-SoA packed math
// (coords pre-doubled, d^2 = add + 3 fma w/ negated q; cvt_u32 clamps negatives)
template<int NCAND, int KSEL, int EPI, int CAP>
__device__ __forceinline__ void sel_body(
    int gp0,
    const float4* __restrict__ qpts4, const float4* __restrict__ cpts4,
    const float* __restrict__ cpairs,
    int* __restrict__ nidx, const float* __restrict__ x2, float* __restrict__ xi,
    unsigned* hist0, unsigned* hist1,
    unsigned* skey, unsigned* sidx,          // [2*64] each
    float* swtE, unsigned* sidxE,            // [2*KSEL]
    unsigned* wpart, int* sstate)
{
    const int b = gp0 >> 12;
    const int t = threadIdx.x, wv = t >> 6, lane = t & 63;
    constexpr int ITER  = NCAND / 256;
    constexpr int PITER = NCAND / 512;

    const float4 qv0 = qpts4[gp0];
    const float4 qv1 = qpts4[gp0 + 1];
    const float4* pb = cpts4 + (size_t)b*NCAND;
    const float*  pbs = cpairs + (size_t)b*NCAND*4;

    unsigned kreg[2][ITER];
    if (t < 16)      ((uint4*)hist0)[t]      = (uint4){0u,0u,0u,0u};
    else if (t < 32) ((uint4*)hist1)[t - 16] = (uint4){0u,0u,0u,0u};
    __syncthreads();

    {
        const float2v nqx0 = {-qv0.x, -qv0.x}, nqy0 = {-qv0.y, -qv0.y};
        const float2v nqz0 = {-qv0.z, -qv0.z}, qw0 = {qv0.w, qv0.w};
        const float2v nqx1 = {-qv1.x, -qv1.x}, nqy1 = {-qv1.y, -qv1.y};
        const float2v nqz1 = {-qv1.z, -qv1.z}, qw1 = {qv1.w, qv1.w};
        #pragma unroll
        for (int pi = 0; pi < PITER; pi++) {
            const int ip = t + 256*pi;
            float4 A  = ((const float4*)pbs)[2*ip];       // 2x0 2x1 2y0 2y1
            float4 Bv = ((const float4*)pbs)[2*ip + 1];   // 2z0 2z1 w0 w1
            float2v xp = {A.x, A.y},  yp = {A.z, A.w};
            float2v zp = {Bv.x, Bv.y}, wp = {Bv.z, Bv.w};
            float2v d0 = wp + qw0;
            d0 = __builtin_elementwise_fma(xp, nqx0, d0);
            d0 = __builtin_elementwise_fma(yp, nqy0, d0);
            d0 = __builtin_elementwise_fma(zp, nqz0, d0);
            float2v d1 = wp + qw1;
            d1 = __builtin_elementwise_fma(xp, nqx1, d1);
            d1 = __builtin_elementwise_fma(yp, nqy1, d1);
            d1 = __builtin_elementwise_fma(zp, nqz1, d1);
            unsigned ka = (unsigned)d0[0], kb = (unsigned)d0[1];
            unsigned kc = (unsigned)d1[0], kd = (unsigned)d1[1];
            kreg[0][2*pi] = ka; kreg[0][2*pi+1] = kb;
            kreg[1][2*pi] = kc; kreg[1][2*pi+1] = kd;
            if ((ka >> 20) < CAP) atomicAdd(&hist0[ka >> 20], 1u);
            if ((kb >> 20) < CAP) atomicAdd(&hist0[kb >> 20], 1u);
            if ((kc >> 20) < CAP) atomicAdd(&hist1[kc >> 20], 1u);
            if ((kd >> 20) < CAP) atomicAdd(&hist1[kd >> 20], 1u);
        }
    }
    __syncthreads();

    // single-wave threshold scan: wave 0 -> q0, wave 1 -> q1
    if (wv < 2) {
        unsigned* H = wv ? hist1 : hist0;
        unsigned h = (lane < CAP) ? H[lane] : 0u;
        unsigned incl = h;
        #pragma unroll
        for (int off = 1; off < 64; off <<= 1) {
            unsigned o = (unsigned)__shfl_up((int)incl, off);
            if (lane >= off) incl += o;
        }
        unsigned excl = incl - h;
        const int base = wv*8;
        if ((int)excl < KSEL && KSEL <= (int)(excl + h)) {
            sstate[base+0] = lane; sstate[base+1] = (int)excl; sstate[base+2] = (int)h;
            sstate[base+3] = ((int)(excl + h) <= 64) ? 1 : 0;
            sstate[base+4] = 0;
        }
        unsigned tot = (unsigned)__shfl((int)incl, 63);
        if (lane == 0 && (int)tot < KSEL) sstate[base+3] = -1;  // fallback flag
    }
    __syncthreads();

    // full-histogram fallback (essentially never taken for this data; kept for
    // correctness when < KSEL candidates lie within the capped d^2 range)
    if (sstate[3] == -1 || sstate[11] == -1) {
        for (int qi = 0; qi < 2; qi++) {
            if (sstate[qi*8+3] != -1) continue;
            ((uint4*)hist0)[t] = (uint4){0u,0u,0u,0u};
            __syncthreads();
            #pragma unroll
            for (int it = 0; it < ITER; it++)
                atomicAdd(&hist0[kreg[qi][it] >> 20], 1u);
            __syncthreads();
            uint4 h4 = ((const uint4*)hist0)[t];
            unsigned hv[4] = {h4.x, h4.y, h4.z, h4.w};
            unsigned tsum = hv[0]+hv[1]+hv[2]+hv[3];
            unsigned incl = tsum;
            #pragma unroll
            for (int off = 1; off < 64; off <<= 1) {
                unsigned o = (unsigned)__shfl_up((int)incl, off);
                if (lane >= off) incl += o;
            }
            if (lane == 63) wpart[wv] = incl;
            __syncthreads();
            unsigned wbase = 0;
            for (int i2 = 0; i2 < wv; i2++) wbase += wpart[i2];
            unsigned excl = wbase + incl - tsum;
            if ((int)excl < KSEL && KSEL <= (int)(excl + tsum)) {
                unsigned cum = excl;
                #pragma unroll
                for (int i2 = 0; i2 < 4; i2++) {
                    unsigned h = hv[i2];
                    if ((int)cum < KSEL && KSEL <= (int)(cum + h)) {
                        sstate[qi*8+0] = t*4 + i2; sstate[qi*8+1] = (int)cum;
                        sstate[qi*8+2] = (int)h;
                        sstate[qi*8+3] = ((int)cum + (int)h <= 64) ? 1 : 0;
                        sstate[qi*8+4] = 0;
                        break;
                    }
                    cum += h;
                }
            }
            __syncthreads();
        }
    }

    if (sstate[3] == 1 && sstate[11] == 1) {
        // both queries fast: unordered per-lane atomic compaction (<=64 each)
        const unsigned P0 = (unsigned)sstate[0];
        const unsigned P1 = (unsigned)sstate[8];
        #pragma unroll
        for (int pi = 0; pi < PITER; pi++) {
            const int ip = t + 256*pi;
            #pragma unroll
            for (int c2 = 0; c2 < 2; c2++) {
                const int j = 2*ip + c2;
                const unsigned k0 = kreg[0][2*pi+c2], k1 = kreg[1][2*pi+c2];
                if ((k0 >> 20) <= P0) {
                    int pos = (int)atomicAdd((unsigned*)&sstate[4], 1u);
                    skey[pos] = k0; sidx[pos] = (unsigned)j;
                }
                if ((k1 >> 20) <= P1) {
                    int pos = (int)atomicAdd((unsigned*)&sstate[12], 1u);
                    skey[64 + pos] = k1; sidx[64 + pos] = (unsigned)j;
                }
            }
        }
    } else {
        #pragma unroll
        for (int qi = 0; qi < 2; qi++) {
            const float4 qv = qi ? qv1 : qv0;
            unsigned P = (unsigned)sstate[qi*8+0];
            int S = sstate[qi*8+1], cntB = sstate[qi*8+2], mode = sstate[qi*8+3];
            int gsh = 20;
            if (mode == 0) {
                for (int round = 1; round < 4; round++) {
                    const int nb  = (round == 3) ? 16 : 256;
                    const int wb  = (round == 3) ? 4 : 8;
                    const int sh  = (round == 1) ? 12 : (round == 2 ? 4 : 0);
                    const int psh = sh + wb;
                    if (t < nb) hist0[t] = 0u;
                    __syncthreads();
                    #pragma unroll
                    for (int it = 0; it < ITER; it++) {
                        unsigned key = kreg[qi][it];
                        if ((key >> psh) == P)
                            atomicAdd(&hist0[(key >> sh) & (nb - 1)], 1u);
                    }
                    __syncthreads();
                    unsigned hv = (t < nb) ? hist0[t] : 0u;
                    unsigned tsum = hv;
                    unsigned incl = tsum;
                    #pragma unroll
                    for (int off = 1; off < 64; off <<= 1) {
                        unsigned o = (unsigned)__shfl_up((int)incl, off);
                        if (lane >= off) incl += o;
                    }
                    if (lane == 63) wpart[wv] = incl;
                    __syncthreads();
                    unsigned wbase = 0;
                    for (int i2 = 0; i2 < wv; i2++) wbase += wpart[i2];
                    unsigned exclT = wbase + incl - tsum;
                    const int need = KSEL - S;
                    if ((int)exclT < need && need <= (int)(exclT + tsum)) {
                        int Snew = S + (int)exclT;
                        int tot  = Snew + (int)tsum;
                        sstate[qi*8+0] = (int)((P << wb) | (unsigned)t);
                        sstate[qi*8+1] = Snew; sstate[qi*8+2] = (int)tsum;
                        sstate[qi*8+3] = (tot <= 64) ? 1 : ((round == 3) ? 2 : 0);
                        sstate[qi*8+4] = 0;
                    }
                    __syncthreads();
                    P = (unsigned)sstate[qi*8+0]; S = sstate[qi*8+1];
                    cntB = sstate[qi*8+2]; mode = sstate[qi*8+3];
                    gsh = sh;
                    if (mode) break;
                }
            }
            if (mode == 1) {
                #pragma unroll
                for (int pi = 0; pi < PITER; pi++) {
                    const int ip = t + 256*pi;
                    #pragma unroll
                    for (int c2 = 0; c2 < 2; c2++) {
                        const int j = 2*ip + c2;
                        unsigned key = kreg[qi][2*pi+c2];
                        if ((key >> gsh) <= P) {
                            int pos = (int)atomicAdd((unsigned*)&sstate[qi*8+4], 1u);
                            skey[qi*64 + pos] = key; sidx[qi*64 + pos] = (unsigned)j;
                        }
                    }
                }
            } else if (mode != 1) {
                if (t < 64) {
                    const unsigned long long lmask = (1ull << lane) - 1ull;
                    int cnt = 0;
                    for (int pass = 0; pass < 2; pass++) {
                        for (int it = 0; it < NCAND/64; it++) {
                            int j = lane + 64*it;
                            float4 cv = pb[j];
                            float dot = fmaf(qv.z, cv.z, fmaf(qv.y, cv.y, qv.x*cv.x));
                            float d2 = fmaxf(fmaf(-2.f, dot, qv.w + cv.w), 0.f);
                            unsigned key = (unsigned)d2;
                            bool f = pass ? (key == P) : (key < P);
                            unsigned long long bal = __ballot(f);
                            if (f) {
                                int pos = cnt + __popcll(bal & lmask);
                                if (pos < 64) { skey[qi*64 + pos] = key; sidx[qi*64 + pos] = (unsigned)j; }
                            }
                            cnt += __popcll(bal);
                        }
                    }
                    if (lane == 0) { sstate[qi*8+1] = min(cnt, 64); sstate[qi*8+2] = 0; }
                }
            }
            __syncthreads();
        }
    }
    __syncthreads();

    if (wv < 2) {
        const int q = wv;
        const int total = sstate[q*8+1] + sstate[q*8+2];
        unsigned long long v = ~0ull;
        if (lane < total)
            v = (((unsigned long long)skey[q*64 + lane]) << 32) | sidx[q*64 + lane];
        #pragma unroll
        for (int k = 2; k <= 64; k <<= 1) {
            #pragma unroll
            for (int jj = k >> 1; jj > 0; jj >>= 1) {
                unsigned long long p = shfl_xor_u64(v, jj);
                bool up = ((lane & k) == 0);
                bool takeMin = (((lane & jj) == 0) == up);
                bool pl = p < v;
                v = (takeMin == pl) ? p : v;
            }
        }
        if (EPI == 0) {
            if (lane < KSEL)
                nidx[(gp0 + q)*KSEL + lane] = b*NCAND + (int)(v & 0xffffffffull);
        } else {
            const float4 qq = q ? qv1 : qv0;
            float wgt = 0.f;
            unsigned si = (unsigned)(v & 0xffffffffull);
            if (lane < KSEL) {
                float4 cv = pb[si];
                float dot = fmaf(qq.z, cv.z, fmaf(qq.y, cv.y, qq.x*cv.x));
                float d2 = fmaxf(fmaf(-2.f, dot, qq.w + cv.w), 0.f);
                // d2 is scaled by 2^28; 1e-8 * 2^14 = 1.6384e-4; the 2^14 factor
                // cancels in the weight normalization below
                wgt = 1.f / (sqrtf(d2) + 1.6384e-4f);
            }
            float ws = wgt;
            ws += __shfl_xor(ws, 1); ws += __shfl_xor(ws, 2); ws += __shfl_xor(ws, 4);
            if (lane < KSEL) {
                swtE[q*KSEL + lane]  = wgt / ws;
                sidxE[q*KSEL + lane] = si;
            }
        }
    }

    if (EPI == 1) {
        __syncthreads();
        const int qi2 = t >> 7, tt = t & 127;
        const float* x2b = x2 + (size_t)b*NCAND*DS;
        float a = 0.f;
        #pragma unroll
        for (int r = 0; r < KSEL; r++)
            a = fmaf(swtE[qi2*KSEL + r], x2b[(size_t)sidxE[qi2*KSEL + r]*DS + tt], a);
        xi[(size_t)(gp0 + qi2)*DS + tt] = a;
    }
}

__global__ __launch_bounds__(256) void k_sel2(
    const float4* __restrict__ p1q, const float4* __restrict__ p2q,
    const float* __restrict__ p1s, const float* __restrict__ p2s,
    int* __restrict__ nidx, const float* __restrict__ x2, float* __restrict__ xi)
{
    __shared__ __align__(16) unsigned hist0[1024], hist1[1024];
    __shared__ __align__(16) unsigned skey[128], sidx[128];
    __shared__ float    swtE[2*KI];
    __shared__ unsigned sidxE[2*KI];
    __shared__ unsigned wpart[8];
    __shared__ int      sstate[20];
    const int bid = blockIdx.x;
    if (bid < M1/2) {
        // kNN-16: p1 vs p1, 4096 candidates; CAP=32 (d^2<0.125 scaled)
        sel_body<NN1, KN, 0, 32>(bid*2, p1q, p1q, p1s, nidx, nullptr, nullptr,
                                 hist0, hist1, skey, sidx, swtE, sidxE, wpart, sstate);
    } else {
        // interp-8: p1 vs p2, 1024 candidates + gather epilogue; CAP=64
        sel_body<NN2, KI, 1, 64>((bid - M1/2)*2, p1q, p2q, p2s, nullptr, x2, xi,
                                 hist0, hist1, skey, sidx, swtE, sidxE, wpart, sstate);
    }
}

// ---------------------------------------------------------------- launch
extern "C" void kernel_launch(void* const* d_in, const int* in_sizes, int n_in,
                              void* d_out, int out_size, void* d_ws, size_t ws_size,
                              hipStream_t stream)
{
    const float* p1 = (const float*)d_in[0];
    const float* x1 = (const float*)d_in[1];
    const int*   o1 = (const int*)d_in[2];
    const float* p2 = (const float*)d_in[3];
    const float* x2 = (const float*)d_in[4];
    const float* W_dense = (const float*)d_in[7];
    const float* b_dense = (const float*)d_in[8];
    const float* g_dense = (const float*)d_in[9];
    const float* bt_dense= (const float*)d_in[10];
    const float* Wq = (const float*)d_in[11];
    const float* Wk = (const float*)d_in[12];
    const float* Wv = (const float*)d_in[13];
    const float* W1 = (const float*)d_in[14];
    const float* b1 = (const float*)d_in[15];
    const float* g1 = (const float*)d_in[16];
    const float* bt1= (const float*)d_in[17];
    const float* W2 = (const float*)d_in[18];
    const float* W_out = (const float*)d_in[20];
    const float* b_out = (const float*)d_in[21];
    const float* g_out = (const float*)d_in[22];
    const float* bt_out= (const float*)d_in[23];

    float* ws   = (float*)d_ws;
    unsigned short* wts  = (unsigned short*)(ws + OFF_WTS);
    float* tmp  = ws + OFF_TMP;
    float* xi   = ws + OFF_XI;
    float* qm   = ws + OFF_Q;
    float* outp = ws + OFF_OUTP;
    int*   nidx = (int*)(ws + OFF_NIDX);
    float* stat = ws + OFF_STAT;
    float4* p1q = (float4*)(ws + OFF_P1Q);
    float4* p2q = (float4*)(ws + OFF_P2Q);
    float* p1s = ws + OFF_P1S;
    float* p2s = ws + OFF_P2S;
    unsigned short* q16 = (unsigned short*)(ws + OFF_Q);
    unsigned short* e16 = (unsigned short*)(ws + OFF_K);
    unsigned short* v16 = (unsigned short*)(ws + OFF_V);
    unsigned short* qw16 = (unsigned short*)(ws + OFF_XD);
    unsigned short* ew16 = (unsigned short*)(ws + OFF_OUTP);
    float* sums_d = stat,      *sumsq_d = stat+256;
    float* sums_h = stat+1024, *sumsq_h = stat+1280;
    float* sums_o = stat+2048, *sumsq_o = stat+2304;
    float* out = (float*)d_out;

    // prolog + weight swizzles, one launch
    SwzParams sp;
    sp.W[0]=W_dense; sp.W[1]=Wq; sp.W[2]=Wk; sp.W[3]=Wv; sp.W[4]=W1; sp.W[5]=W2; sp.W[6]=W_out;
    sp.hi[0]=wts+WDH; sp.hi[1]=wts+WQH; sp.hi[2]=wts+WKH; sp.hi[3]=wts+WVH;
    sp.hi[4]=wts+W1H; sp.hi[5]=wts+W2H; sp.hi[6]=wts+WOH;
    sp.lo[0]=wts+WDL; sp.lo[1]=wts+WQL; sp.lo[2]=wts+WKL; sp.lo[3]=wts+WVL;
    sp.lo[4]=wts+W1L; sp.lo[5]=wts+W2L; sp.lo[6]=wts+WOL;
    sp.N[0]=128; sp.N[1]=128; sp.N[2]=128; sp.N[3]=128; sp.N[4]=128; sp.N[5]=128; sp.N[6]=256;
    sp.fid0[0]=0; sp.fid0[1]=16; sp.fid0[2]=48; sp.fid0[3]=80; sp.fid0[4]=112;
    sp.fid0[5]=144; sp.fid0[6]=176; sp.fid0[7]=272;
    k_prolog<<<NPRO + 68, 256, 0, stream>>>(p1, o1, p2, out, stat, p1q, p2q, p1s, p2s, sp);

    // both top-K selects (kNN-16 + interp-8 with gather epilogue), one launch
    k_sel2<<<M1, 256, 0, stream>>>(p1q, p2q, p1s, p2s, nidx, x2, xi);

    // dense_mlp GEMM (stats fused, N-split x2); bn+relu applied downstream
    k_gemm_mf<128,64,0,1,0,2><<<dim3(M1/64,2), 256, 0, stream>>>(x1, wts+WDH, wts+WDL,
        b_dense, tmp, nullptr, sums_d, sumsq_d, nullptr, nullptr, nullptr, nullptr);

    // q, k, v projections — one launch (y=seg, z=N-split x2); BN(dense) fused;
    // bf16 outputs: q / e=xd-k / v2=v+xd
    k_gemm_mf<128,128,3,0,1,2><<<dim3(M1/64,3,2), 256, 0, stream>>>(tmp, wts+WQH, wts+WQL,
        nullptr, qm, xi, nullptr, nullptr, sums_d, sumsq_d, g_dense, bt_dense);

    // h@W1 = q@W1 + e@W1 (MFMA linearity) — bf16 GEMMs (y=q/e, z=N-split x2)
    k_gemm_qe<<<dim3(M1/64, 2, 2), 256, 0, stream>>>(q16, e16, wts+W1H, b1, qw16, ew16);
    // BN stats over h computed WITHOUT materializing h (bf16 streams)
    k_hstat<<<M1/16, 256, 0, stream>>>(qw16, ew16, nidx, sums_h, sumsq_h);

    // attn: h formed inline from bf16 qw/ew, BN finalize inline, bf16 v2
    k_attn3<<<M1/4, 256, 0, stream>>>(qw16, ew16, sums_h, sumsq_h, g1, bt1,
        wts+W2H, v16, nidx, tmp);

    // output mlp (stats fused, N-split x4) -> bn+relu (finalize inline, float4)
    k_gemm_mf<256,192,2,1,0,4><<<dim3(M1/64,4), 256, 0, stream>>>(tmp, wts+WOH, wts+WOL,
        b_out, outp, x1, sums_o, sumsq_o, nullptr, nullptr, nullptr, nullptr);
    k_bnrelu<<<(M1*DOUT/4)/256, 256, 0, stream>>>((const float4*)outp, sums_o, sumsq_o,
        g_out, bt_out, 1.f/(float)M1, (float4*)(out + OUT_X), (size_t)M1*DOUT/4, DOUT);
}